// Round 5
// baseline (282.732 us; speedup 1.0000x reference)
//
#include <hip/hip_runtime.h>
#include <stdint.h>

#define EMB 1024
#define LROW 40   // attn-kernel LDS pitch (u16)

typedef unsigned short u16;
typedef __attribute__((ext_vector_type(8))) unsigned short u16x8;
typedef __attribute__((ext_vector_type(8))) __bf16 bf16x8;
typedef __attribute__((ext_vector_type(4))) float f32x4;

__device__ __forceinline__ u16 f2bf(float f) {
  union { float f; uint32_t u; } x; x.f = f;
  uint32_t u = x.u;
  u += 0x7fff + ((u >> 16) & 1u);   // round-to-nearest-even
  return (u16)(u >> 16);
}

// 8x f32 -> bf16x8 via native casts (v_cvt_pk_bf16_f32).
__device__ __forceinline__ bf16x8 cvt8(float4 a, float4 b) {
  bf16x8 r;
  r[0] = (__bf16)a.x; r[1] = (__bf16)a.y; r[2] = (__bf16)a.z; r[3] = (__bf16)a.w;
  r[4] = (__bf16)b.x; r[5] = (__bf16)b.y; r[6] = (__bf16)b.z; r[7] = (__bf16)b.w;
  return r;
}

// Async global->LDS, 16B per lane. LDS dest is wave-uniform base + lane*16.
__device__ __forceinline__ void gl16(const u16* g, u16* l) {
  __builtin_amdgcn_global_load_lds(
      (const __attribute__((address_space(1))) void*)g,
      (__attribute__((address_space(3))) void*)l, 16, 0, 0);
}

// XCD-chunked block swizzle (m157; requires nwg % 8 == 0 -- 1536/512 both ok).
__device__ __forceinline__ int xcd_logical(int orig, int nwg) {
  return (orig & 7) * (nwg >> 3) + (orig >> 3);
}

// ---------------------------------------------------------------------------
// Weight cvt: y-indexed (src,dst) pairs, each exactly EMB*EMB elements.
// ---------------------------------------------------------------------------
__global__ __launch_bounds__(256) void cvtw_kernel(
    const float* __restrict__ s0, u16* __restrict__ d0,
    const float* __restrict__ s1, u16* __restrict__ d1,
    const float* __restrict__ s2, u16* __restrict__ d2,
    const float* __restrict__ s3, u16* __restrict__ d3)
{
  const float* s; u16* d;
  switch (blockIdx.y) {
    case 0:  s = s0; d = d0; break;
    case 1:  s = s1; d = d1; break;
    case 2:  s = s2; d = d2; break;
    default: s = s3; d = d3; break;
  }
  const size_t i = (size_t)blockIdx.x * 256 + threadIdx.x;
  const float4* f = (const float4*)(s + i * 8);
  const float4 lo = f[0], hi = f[1];
  *(bf16x8*)(d + i * 8) = cvt8(lo, hi);
}

// ---------------------------------------------------------------------------
// Fused QKV projection, 2-phase double-buffered K-loop (T3 minimal + T4):
//   ONE raw s_barrier per K-step; counted vmcnt(4) leaves the 4 X-prefetch
//   f32 loads in flight across the barrier (they are the 4 newest vmem ops;
//   gl16s -- which the barrier must guarantee -- are older, so vmcnt(4)
//   proves them drained). sched_barrier(0) pins gl16-before-X-load issue
//   order and fences MFMA-vs-lgkmcnt hoisting (rule #18).
// Race ledger: buf^1 is written only after the barrier that followed
//   lgkmcnt(0)-drained reads of it by ALL waves; staging into buf^1 is
//   proven complete (lgkmcnt(0) for ds_write, vmcnt(4) for gl16) before the
//   barrier that precedes reads of it. One barrier per iter, all waves.
// XCD chunking + bank swizzle as round 4 (verified: conflicts = 0).
// ---------------------------------------------------------------------------
__global__ __launch_bounds__(256, 3) void qkv_fused_kernel(
    const float* __restrict__ Vx, const float* __restrict__ Kx,
    const float* __restrict__ Qx, const u16* __restrict__ Wb,
    const float* __restrict__ Bv, const float* __restrict__ Bk,
    const float* __restrict__ Bq,
    u16* __restrict__ cv, u16* __restrict__ ck, u16* __restrict__ cq,
    int N, int K, int M)
{
  __shared__ __attribute__((aligned(16))) u16 Al[2][128 * 32];
  __shared__ __attribute__((aligned(16))) u16 Bl[2][128 * 32];

  const int nwg = (N >> 7) * (M >> 7) * 3;
  const int logical = xcd_logical(blockIdx.x, nwg);
  const int per_z = (N >> 7) * (M >> 7);
  const int z = logical / per_z;
  const int rem = logical - z * per_z;
  const int nbx = N >> 7;
  const int by = rem / nbx, bx = rem - by * nbx;

  const float* X; const u16* W; const float* Bias; u16* C;
  switch (z) {
    case 0:  X = Vx; W = Wb;                   Bias = Bv; C = cv; break;
    case 1:  X = Kx; W = Wb + EMB * EMB;       Bias = Bk; C = ck; break;
    default: X = Qx; W = Wb + 2 * EMB * EMB;   Bias = Bq; C = cq; break;
  }

  const int tid  = threadIdx.x;
  const int lane = tid & 63;
  const int w    = tid >> 6;
  const int wm = w >> 1, wn = w & 1;
  const int r16 = lane & 15, quad = lane >> 4;
  const int bm = by * 128, bn = bx * 128;

  // A staging (reg -> swizzled ds_write)
  const int s0 = tid, s1 = tid + 256;
  const int r0 = s0 >> 2, c0 = s0 & 3;
  const int r1 = s1 >> 2, c1 = s1 & 3;
  const int lA0 = r0 * 32 + ((c0 ^ ((r0 >> 1) & 3)) * 8);
  const int lA1 = r1 * 32 + ((c1 ^ ((r1 >> 1) & 3)) * 8);
  const size_t xo0 = (size_t)(bm + r0) * K + c0 * 8;
  const size_t xo1 = (size_t)(bm + r1) * K + c1 * 8;

  // B staging (gl16, linear dest, pre-swizzled source)
  const int bs0 = w * 64 + lane, bs1 = bs0 + 256;
  const int br0 = bs0 >> 2, bc0 = ((bs0 & 3) ^ ((br0 >> 1) & 3)) * 8;
  const int br1 = bs1 >> 2, bc1 = ((bs1 & 3) ^ ((br1 >> 1) & 3)) * 8;
  const u16* srcB0 = W + (size_t)(bn + br0) * K + bc0;
  const u16* srcB1 = W + (size_t)(bn + br1) * K + bc1;
  const int dB0o = (w * 64) * 8, dB1o = dB0o + 256 * 8;

  // frag reads
  const int swz = (quad ^ ((r16 >> 1) & 3)) * 8;
  int offA[4], offB[4];
#pragma unroll
  for (int t = 0; t < 4; t++) {
    offA[t] = (wm * 64 + t * 16 + r16) * 32 + swz;
    offB[t] = (wn * 64 + t * 16 + r16) * 32 + swz;
  }

  f32x4 acc[4][4];
#pragma unroll
  for (int i = 0; i < 4; i++)
#pragma unroll
    for (int j = 0; j < 4; j++)
      acc[i][j] = f32x4{0.f, 0.f, 0.f, 0.f};

  // ---- prologue: tile0 -> buf0; X tile1 -> regs; counted drain; barrier
  float4 xa0 = *(const float4*)(X + xo0), xa1 = *(const float4*)(X + xo0 + 4);
  float4 xb0 = *(const float4*)(X + xo1), xb1 = *(const float4*)(X + xo1 + 4);
  *(bf16x8*)&Al[0][lA0] = cvt8(xa0, xa1);
  *(bf16x8*)&Al[0][lA1] = cvt8(xb0, xb1);
  gl16(srcB0, &Bl[0][dB0o]);
  gl16(srcB1, &Bl[0][dB1o]);
  __builtin_amdgcn_sched_barrier(0);
  xa0 = *(const float4*)(X + xo0 + 32); xa1 = *(const float4*)(X + xo0 + 36);
  xb0 = *(const float4*)(X + xo1 + 32); xb1 = *(const float4*)(X + xo1 + 36);
  asm volatile("s_waitcnt vmcnt(4) lgkmcnt(0)\n\ts_barrier" ::: "memory");

  for (int k0 = 0; k0 < K; k0 += 32) {
    const int cur = (k0 >> 5) & 1, nxt = cur ^ 1;
    const int kn  = (k0 + 32) & (K - 1);
    const int kn2 = (k0 + 64) & (K - 1);

    // stage tile t+1 into buf[nxt] (regs hold its X data; compiler inserts
    // the dependency vmcnt wait -- exactly the 4 loads cvt needs)
    *(bf16x8*)&Al[nxt][lA0] = cvt8(xa0, xa1);
    *(bf16x8*)&Al[nxt][lA1] = cvt8(xb0, xb1);
    gl16(srcB0 + kn, &Bl[nxt][dB0o]);
    gl16(srcB1 + kn, &Bl[nxt][dB1o]);
    __builtin_amdgcn_sched_barrier(0);   // pin: gl16 issued BEFORE X loads
    xa0 = *(const float4*)(X + xo0 + kn2); xa1 = *(const float4*)(X + xo0 + kn2 + 4);
    xb0 = *(const float4*)(X + xo1 + kn2); xb1 = *(const float4*)(X + xo1 + kn2 + 4);

    bf16x8 a[4], b[4];
#pragma unroll
    for (int t = 0; t < 4; t++) a[t] = *(const bf16x8*)&Al[cur][offA[t]];
#pragma unroll
    for (int t = 0; t < 4; t++) b[t] = *(const bf16x8*)&Bl[cur][offB[t]];
    asm volatile("s_waitcnt lgkmcnt(0)" ::: "memory");
    __builtin_amdgcn_sched_barrier(0);   // rule #18: no MFMA hoist past wait

#pragma unroll
    for (int tm = 0; tm < 4; tm++)
#pragma unroll
      for (int tn = 0; tn < 4; tn++)
        acc[tm][tn] = __builtin_amdgcn_mfma_f32_16x16x32_bf16(a[tm], b[tn], acc[tm][tn], 0, 0, 0);

    // counted drain: 4 newest vmem = X(t+2) loads stay in flight; the 2
    // gl16 into buf[nxt] (older) are proven complete. One barrier per iter.
    asm volatile("s_waitcnt vmcnt(4)\n\ts_barrier" ::: "memory");
  }

  // C/D layout: col = lane&15, row = quad*4 + reg (verified m89/m91)
#pragma unroll
  for (int tn = 0; tn < 4; tn++) {
    const int col = bn + wn * 64 + tn * 16 + r16;
    const float bias = Bias[col];
#pragma unroll
    for (int tm = 0; tm < 4; tm++) {
      const int row0 = bm + wm * 64 + tm * 16 + quad * 4;
#pragma unroll
      for (int r = 0; r < 4; r++)
        C[(size_t)(row0 + r) * N + col] = f2bf(acc[tm][tn][r] + bias);
    }
  }
}

// ---------------------------------------------------------------------------
// Out projection: X bf16, W bf16, C f32. Same 2-phase dbuf; all staging is
// gl16 so the end-of-iter drain is vmcnt(0) (4 gl16s issued a full MFMA
// phase earlier -- mostly hidden). One barrier per K-step.
// ---------------------------------------------------------------------------
__global__ __launch_bounds__(256, 3) void out_gemm_kernel(
    const u16* __restrict__ X, const u16* __restrict__ W,
    const float* __restrict__ Bias, float* __restrict__ C, int N, int K, int M)
{
  __shared__ __attribute__((aligned(16))) u16 Al[2][128 * 32];
  __shared__ __attribute__((aligned(16))) u16 Bl[2][128 * 32];

  const int nwg = (N >> 7) * (M >> 7);
  const int logical = xcd_logical(blockIdx.x, nwg);
  const int nbx = N >> 7;
  const int by = logical / nbx, bx = logical - by * nbx;

  const int tid  = threadIdx.x;
  const int lane = tid & 63;
  const int w    = tid >> 6;
  const int wm = w >> 1, wn = w & 1;
  const int r16 = lane & 15, quad = lane >> 4;
  const int bm = by * 128, bn = bx * 128;

  const int s0 = w * 64 + lane, s1 = s0 + 256;
  const int r0 = s0 >> 2, c0 = ((s0 & 3) ^ ((r0 >> 1) & 3)) * 8;
  const int r1 = s1 >> 2, c1 = ((s1 & 3) ^ ((r1 >> 1) & 3)) * 8;

  const u16* srcA0 = X + (size_t)(bm + r0) * K + c0;
  const u16* srcA1 = X + (size_t)(bm + r1) * K + c1;
  const u16* srcB0 = W + (size_t)(bn + r0) * K + c0;
  const u16* srcB1 = W + (size_t)(bn + r1) * K + c1;

  const int dA0o = (w * 64) * 8, dA1o = dA0o + 256 * 8;

  const int swz = (quad ^ ((r16 >> 1) & 3)) * 8;
  int offA[4], offB[4];
#pragma unroll
  for (int t = 0; t < 4; t++) {
    offA[t] = (wm * 64 + t * 16 + r16) * 32 + swz;
    offB[t] = (wn * 64 + t * 16 + r16) * 32 + swz;
  }

  f32x4 acc[4][4];
#pragma unroll
  for (int i = 0; i < 4; i++)
#pragma unroll
    for (int j = 0; j < 4; j++)
      acc[i][j] = f32x4{0.f, 0.f, 0.f, 0.f};

  // prologue: tile0 -> buf0
  gl16(srcA0, &Al[0][dA0o]);
  gl16(srcA1, &Al[0][dA1o]);
  gl16(srcB0, &Bl[0][dA0o]);
  gl16(srcB1, &Bl[0][dA1o]);
  asm volatile("s_waitcnt vmcnt(0)\n\ts_barrier" ::: "memory");

  for (int k0 = 0; k0 < K; k0 += 32) {
    const int cur = (k0 >> 5) & 1, nxt = cur ^ 1;
    const int kn = (k0 + 32) & (K - 1);

    gl16(srcA0 + kn, &Al[nxt][dA0o]);
    gl16(srcA1 + kn, &Al[nxt][dA1o]);
    gl16(srcB0 + kn, &Bl[nxt][dA0o]);
    gl16(srcB1 + kn, &Bl[nxt][dA1o]);

    bf16x8 a[4], b[4];
#pragma unroll
    for (int t = 0; t < 4; t++) a[t] = *(const bf16x8*)&Al[cur][offA[t]];
#pragma unroll
    for (int t = 0; t < 4; t++) b[t] = *(const bf16x8*)&Bl[cur][offB[t]];
    asm volatile("s_waitcnt lgkmcnt(0)" ::: "memory");
    __builtin_amdgcn_sched_barrier(0);

#pragma unroll
    for (int tm = 0; tm < 4; tm++)
#pragma unroll
      for (int tn = 0; tn < 4; tn++)
        acc[tm][tn] = __builtin_amdgcn_mfma_f32_16x16x32_bf16(a[tm], b[tn], acc[tm][tn], 0, 0, 0);

    asm volatile("s_waitcnt vmcnt(0)\n\ts_barrier" ::: "memory");
  }

#pragma unroll
  for (int tn = 0; tn < 4; tn++) {
    const int col = bn + wn * 64 + tn * 16 + r16;
    const float bias = Bias[col];
#pragma unroll
    for (int tm = 0; tm < 4; tm++) {
      const int row0 = bm + wm * 64 + tm * 16 + quad * 4;
#pragma unroll
      for (int r = 0; r < 4; r++)
        C[(size_t)(row0 + r) * N + col] = acc[tm][tn][r] + bias;
    }
  }
}

// ---------------------------------------------------------------------------
// Per-token head-mixing attention (unchanged).
// ---------------------------------------------------------------------------
__global__ __launch_bounds__(256, 4) void attn_heads_kernel(
    const u16* Q, const u16* Km, const u16* V, u16* O)
{
  __shared__ __attribute__((aligned(16))) u16 P[4][16 * LROW];
  __shared__ __attribute__((aligned(16))) u16 VT[4][64 * LROW];

  const int tid = threadIdx.x, lane = tid & 63, w = tid >> 6;
  const int r16 = lane & 15, quad = lane >> 4;
  const size_t base = ((size_t)blockIdx.x * 4 + w) * EMB;

  const bf16x8 aq0 = *(const bf16x8*)&Q[base + r16 * 64 + quad * 8];
  const bf16x8 aq1 = *(const bf16x8*)&Q[base + r16 * 64 + 32 + quad * 8];
  const bf16x8 bk0 = *(const bf16x8*)&Km[base + r16 * 64 + quad * 8];
  const bf16x8 bk1 = *(const bf16x8*)&Km[base + r16 * 64 + 32 + quad * 8];

  const u16x8 v0 = *(const u16x8*)&V[base + lane * 16];
  const u16x8 v1 = *(const u16x8*)&V[base + lane * 16 + 8];
  const u16x8 z8 = {0, 0, 0, 0, 0, 0, 0, 0};
  *(u16x8*)&VT[w][lane * LROW + 16] = z8;
  *(u16x8*)&VT[w][lane * LROW + 24] = z8;
  const int g = lane >> 2, dbase = (lane & 3) * 16;
#pragma unroll
  for (int i = 0; i < 8; i++) {
    VT[w][(dbase + i) * LROW + g]     = v0[i];
    VT[w][(dbase + 8 + i) * LROW + g] = v1[i];
  }

  f32x4 s = f32x4{0.f, 0.f, 0.f, 0.f};
  s = __builtin_amdgcn_mfma_f32_16x16x32_bf16(aq0, bk0, s, 0, 0, 0);
  s = __builtin_amdgcn_mfma_f32_16x16x32_bf16(aq1, bk1, s, 0, 0, 0);

  float p[4];
#pragma unroll
  for (int r = 0; r < 4; r++) {
    float v = s[r] * 0.125f;
    float m = v;
#pragma unroll
    for (int d = 8; d; d >>= 1) m = fmaxf(m, __shfl_xor(m, d, 16));
    float e = __expf(v - m);
    float sum = e;
#pragma unroll
    for (int d = 8; d; d >>= 1) sum += __shfl_xor(sum, d, 16);
    p[r] = e / sum;
  }

#pragma unroll
  for (int r = 0; r < 4; r++) {
    P[w][(quad * 4 + r) * LROW + r16]      = f2bf(p[r]);
    P[w][(quad * 4 + r) * LROW + 16 + r16] = 0;
  }
  __syncthreads();

  const bf16x8 pa = *(const bf16x8*)&P[w][r16 * LROW + quad * 8];

#pragma unroll
  for (int c = 0; c < 4; c++) {
    const bf16x8 bvv = *(const bf16x8*)&VT[w][(c * 16 + r16) * LROW + quad * 8];
    f32x4 o = f32x4{0.f, 0.f, 0.f, 0.f};
    o = __builtin_amdgcn_mfma_f32_16x16x32_bf16(pa, bvv, o, 0, 0, 0);
#pragma unroll
    for (int r = 0; r < 4; r++)
      O[base + (size_t)(quad * 4 + r) * 64 + c * 16 + r16] = f2bf(o[r]);
  }
}

// ---------------------------------------------------------------------------
// Orchestration (unchanged from round 4).
// ---------------------------------------------------------------------------
extern "C" void kernel_launch(void* const* d_in, const int* in_sizes, int n_in,
                              void* d_out, int out_size, void* d_ws, size_t ws_size,
                              hipStream_t stream)
{
  const float* values = (const float*)d_in[0];
  const float* keys   = (const float*)d_in[1];
  const float* query  = (const float*)d_in[2];
  const float* Wv = (const float*)d_in[3];
  const float* bv = (const float*)d_in[4];
  const float* Wk = (const float*)d_in[5];
  const float* bk = (const float*)d_in[6];
  const float* Wq = (const float*)d_in[7];
  const float* bq = (const float*)d_in[8];
  const float* Wo = (const float*)d_in[9];
  const float* bo = (const float*)d_in[10];

  const int M = in_sizes[0] / EMB;   // 8192 tokens
  const int N = EMB, K = EMB;

  u16* q    = (u16*)d_ws;
  u16* kbuf = q + (size_t)M * EMB;
  u16* v    = (u16*)d_out;
  u16* wb   = v + (size_t)M * EMB;
  u16* ao   = q;

  const size_t base_ws = (size_t)2 * M * EMB * sizeof(u16);
  const bool wo_in_ws = ws_size >= base_ws + (size_t)EMB * EMB * sizeof(u16);
  u16* wob = wo_in_ws ? kbuf + (size_t)M * EMB : kbuf;

  dim3 blk(256, 1, 1);
  dim3 cwg(EMB * EMB / 8 / 256, wo_in_ws ? 4 : 3, 1);

  hipLaunchKernelGGL(cvtw_kernel, cwg, blk, 0, stream,
                     Wv, wb, Wk, wb + EMB * EMB, Wq, wb + 2 * EMB * EMB, Wo, wob);
  hipLaunchKernelGGL(qkv_fused_kernel, dim3((N / 128) * (M / 128) * 3, 1, 1), blk, 0, stream,
                     values, keys, query, wb, bv, bk, bq, v, kbuf, q, N, K, M);
  hipLaunchKernelGGL(attn_heads_kernel, dim3(M / 4, 1, 1), blk, 0, stream,
                     q, kbuf, v, ao);
  if (!wo_in_ws)
    hipLaunchKernelGGL(cvtw_kernel, dim3(EMB * EMB / 8 / 256, 1, 1), blk, 0, stream,
                       Wo, wob, (const float*)nullptr, (u16*)nullptr,
                       (const float*)nullptr, (u16*)nullptr,
                       (const float*)nullptr, (u16*)nullptr);
  hipLaunchKernelGGL(out_gemm_kernel, dim3((N / 128) * (M / 128), 1, 1), blk, 0, stream,
                     ao, wob, bo, (float*)d_out, N, K, M);
}